// Round 2
// baseline (271.564 us; speedup 1.0000x reference)
//
#include <hip/hip_runtime.h>

// SSIM (window=8 box sums) over 96 images of 512x512 fp32.
// v2: wave-autonomous design. One 64-lane wave per (image, 16-row strip); each
// lane owns 8 contiguous columns (two float4 loads per image per row). Vertical
// box sums slide in registers (outgoing row re-loaded from cache instead of a
// register ring). Horizontal 8-window sum = intra-wave prefix sums + one
// __shfl_down(P,1) neighbor exchange: out[j] = suffix_own(j) + prefix_next(j).
// No __syncthreads, no LDS tiles — nothing but VALU, loads, and bpermute.

#define W 512
#define H 512
#define OW 505
#define OH 505
#define TH 16
#define NSTRIP ((OH + TH - 1) / TH)   // 32
#define NIMG 96
#define NPIX (96.0 * 505.0 * 505.0)   // 24482400

__device__ __forceinline__ void unpack8(const float* p, float v[8]) {
    float4 a = *(const float4*)p;
    float4 b = *(const float4*)(p + 4);
    v[0] = a.x; v[1] = a.y; v[2] = a.z; v[3] = a.w;
    v[4] = b.x; v[5] = b.y; v[6] = b.z; v[7] = b.w;
}

__global__ void zero_ws(double* p) { *p = 0.0; }

__global__ void finalize(const double* p, float* out) {
    out[0] = 1.0f - (float)(*p / NPIX);
}

__global__ void __launch_bounds__(64, 3)
ssim_main(const float* __restrict__ gt, const float* __restrict__ ni,
          double* __restrict__ acc_out)
{
    const int lane = threadIdx.x;               // 0..63
    const int img  = blockIdx.y;
    const int R0   = blockIdx.x * TH;           // first output row of strip
    const int R1   = min(R0 + TH, OH);
    const int col0 = lane * 8;                  // lane owns cols col0..col0+7

    const float C1 = 1e-4f, C2 = 9e-4f;

    const float* gx = gt + (size_t)img * (W * H) + col0;
    const float* gy = ni + (size_t)img * (W * H) + col0;

    // vertical sliding sums over the 8-row window, per owned column
    float vsx[8], vsy[8], vsq[8], vsp[8];   // sum x, sum y, sum(x^2+y^2), sum(x*y)
#pragma unroll
    for (int c = 0; c < 8; ++c) { vsx[c] = 0.f; vsy[c] = 0.f; vsq[c] = 0.f; vsp[c] = 0.f; }

    // warm-up: accumulate rows R0..R0+6 (all < 512)
#pragma unroll
    for (int k = 0; k < 7; ++k) {
        float xn[8], yn[8];
        unpack8(gx + (size_t)(R0 + k) * W, xn);
        unpack8(gy + (size_t)(R0 + k) * W, yn);
#pragma unroll
        for (int c = 0; c < 8; ++c) {
            vsx[c] += xn[c]; vsy[c] += yn[c];
            vsq[c] += xn[c] * xn[c] + yn[c] * yn[c];
            vsp[c] += xn[c] * yn[c];
        }
    }

    float acc = 0.f;

    for (int r = R0; r < R1; ++r) {
        // incoming row r+7 (<= 511); outgoing row r-1 re-loaded from cache
        float xn[8], yn[8];
        unpack8(gx + (size_t)(r + 7) * W, xn);
        unpack8(gy + (size_t)(r + 7) * W, yn);
        if (r > R0) {               // wave-uniform branch
            float xo[8], yo[8];
            unpack8(gx + (size_t)(r - 1) * W, xo);
            unpack8(gy + (size_t)(r - 1) * W, yo);
#pragma unroll
            for (int c = 0; c < 8; ++c) {
                vsx[c] -= xo[c]; vsy[c] -= yo[c];
                vsq[c] -= xo[c] * xo[c] + yo[c] * yo[c];
                vsp[c] -= xo[c] * yo[c];
            }
        }
#pragma unroll
        for (int c = 0; c < 8; ++c) {
            vsx[c] += xn[c]; vsy[c] += yn[c];
            vsq[c] += xn[c] * xn[c] + yn[c] * yn[c];
            vsp[c] += xn[c] * yn[c];
        }

        // horizontal 8-window sums: prefix within lane + neighbor-lane prefix.
        // out[0] = own total; out[j] = (T - P[j-1]) + P_next[j-1], j=1..7.
        // Lane 63's j>=1 outputs consume shuffle garbage but are predicated out.
        float Sx[8], Sy[8], Sq[8], Sp[8];
#define HORIZ(vs, S) {                                                        \
            float P[8];                                                       \
            P[0] = vs[0];                                                     \
            _Pragma("unroll") for (int j = 1; j < 8; ++j) P[j] = P[j-1] + vs[j]; \
            float T = P[7];                                                   \
            S[0] = T;                                                         \
            _Pragma("unroll") for (int j = 1; j < 8; ++j)                     \
                S[j] = (T - P[j-1]) + __shfl_down(P[j-1], 1);                 \
        }
        HORIZ(vsx, Sx)
        HORIZ(vsy, Sy)
        HORIZ(vsq, Sq)
        HORIZ(vsp, Sp)
#undef HORIZ

#pragma unroll
        for (int j = 0; j < 8; ++j) {
            float sx = Sx[j], sy = Sy[j];
            float mu12 = sx * sy;
            float n1 = 2.f * mu12 + C1;
            float n2 = 2.f * (Sp[j] - mu12) + C2;
            float sx2 = sx * sx, sy2 = sy * sy;
            float d1 = sx2 + sy2 + C1;
            float d2 = (Sq[j] - sx2 - sy2) + C2;
            float sv = (n1 * n2) / (d1 * d2);
            if (col0 + j < OW) acc += sv;   // only lane 63 is partially valid
        }
    }

    // wave reduction -> one double atomic per wave
#pragma unroll
    for (int off = 32; off; off >>= 1) acc += __shfl_down(acc, off);
    if (lane == 0) atomicAdd(acc_out, (double)acc);
}

extern "C" void kernel_launch(void* const* d_in, const int* in_sizes, int n_in,
                              void* d_out, int out_size, void* d_ws, size_t ws_size,
                              hipStream_t stream) {
    const float* gt = (const float*)d_in[0];
    const float* ni = (const float*)d_in[1];
    double* acc = (double*)d_ws;   // 8 bytes scratch, re-zeroed every call

    zero_ws<<<1, 1, 0, stream>>>(acc);
    dim3 grid(NSTRIP, NIMG);
    ssim_main<<<grid, 64, 0, stream>>>(gt, ni, acc);
    finalize<<<1, 1, 0, stream>>>(acc, (float*)d_out);
}

// Round 3
// 251.101 us; speedup vs baseline: 1.0815x; 1.0815x over previous
//
#include <hip/hip_runtime.h>

// SSIM (window=8 box sums) over 96 images of 512x512 fp32.
// v3 = v1 structure (128 threads x float4 = full 512-wide row, register ring
// for the vertical sliding window, LDS for the horizontal 8-sum) with:
//  - TH=16 (3072 blocks -> 12 blocks/CU demand, was 6)
//  - 4 quantities instead of 5 (sum of x^2+y^2 combined)
//  - single-buffer LDS (8.3 KB) + 2 barriers/row -> occupancy not LDS-capped
//  - v_rcp_f32 instead of IEEE divide in the SSIM epilogue

#define W 512
#define H 512
#define OW 505
#define OH 505
#define TH 16
#define NSTRIP ((OH + TH - 1) / TH)   // 32
#define NIMG 96
#define NPIX (96.0 * 505.0 * 505.0)   // 24482400

__device__ __forceinline__ float4 ld4(const float* p) { return *(const float4*)p; }
__device__ __forceinline__ float4 f4add(float4 a, float4 b) {
    return make_float4(a.x + b.x, a.y + b.y, a.z + b.z, a.w + b.w);
}
__device__ __forceinline__ float4 f4sub(float4 a, float4 b) {
    return make_float4(a.x - b.x, a.y - b.y, a.z - b.z, a.w - b.w);
}
__device__ __forceinline__ float4 f4mul(float4 a, float4 b) {
    return make_float4(a.x * b.x, a.y * b.y, a.z * b.z, a.w * b.w);
}

__global__ void zero_ws(double* p) { *p = 0.0; }

__global__ void finalize(const double* p, float* out) {
    out[0] = 1.0f - (float)(*p / NPIX);
}

__global__ void __launch_bounds__(128, 4)
ssim_main(const float* __restrict__ gt, const float* __restrict__ ni,
          double* __restrict__ acc_out)
{
    const int t   = threadIdx.x;      // 0..127
    const int c0  = t * 4;            // base column (0..508)
    const int img = blockIdx.y;
    const int R0  = blockIdx.x * TH;  // first output row of strip (mult of 8)
    const int R1  = min(R0 + TH, OH);

    const float C1 = 1e-4f;
    const float C2 = 9e-4f;

    const float* gx = gt + (size_t)img * (W * H) + c0;
    const float* gy = ni + (size_t)img * (W * H) + c0;

    // single-buffered vertical sums: [quantity][column]; width 520 so threads
    // 126/127 can read past 512 (garbage, predicated out of the final sum).
    __shared__ float vbuf[4][520];
    __shared__ float wpart[2];

    float4 ring_x[8], ring_y[8];
    float4 vsx = make_float4(0, 0, 0, 0);   // sum x
    float4 vsy = make_float4(0, 0, 0, 0);   // sum y
    float4 vsq = make_float4(0, 0, 0, 0);   // sum x^2 + y^2
    float4 vsp = make_float4(0, 0, 0, 0);   // sum x*y

    // warm-up: rows R0..R0+6 -> ring slots 0..6; slot 7 = zeros (no row leaves
    // the window at r == R0).
#pragma unroll
    for (int k = 0; k < 7; ++k) {
        float4 x = ld4(gx + (size_t)(R0 + k) * W);
        float4 y = ld4(gy + (size_t)(R0 + k) * W);
        ring_x[k] = x; ring_y[k] = y;
        vsx = f4add(vsx, x);
        vsy = f4add(vsy, y);
        vsq = f4add(vsq, f4add(f4mul(x, x), f4mul(y, y)));
        vsp = f4add(vsp, f4mul(x, y));
    }
    ring_x[7] = make_float4(0, 0, 0, 0);
    ring_y[7] = make_float4(0, 0, 0, 0);

    // prefetch first new row (R0+7 <= 511 always)
    float4 px = ld4(gx + (size_t)(R0 + 7) * W);
    float4 py = ld4(gy + (size_t)(R0 + 7) * W);

    float acc = 0.0f;

#define HORIZ(q, v) {                                                     \
        float4 n1 = *(float4*)&vbuf[q][c0 + 4];                           \
        float4 n2 = *(float4*)&vbuf[q][c0 + 8];                           \
        float s = ((v.x + v.y) + (v.z + v.w)) +                           \
                  ((n1.x + n1.y) + (n1.z + n1.w));                        \
        B[q][0] = s;                                                      \
        s += n2.x - v.x; B[q][1] = s;                                     \
        s += n2.y - v.y; B[q][2] = s;                                     \
        s += n2.z - v.z; B[q][3] = s;                                     \
    }

#define ROWBODY(k, slot) {                                                \
        const int r = rbase + (k);                                        \
        if (r < R1) { /* block-uniform */                                 \
            float4 cx = px, cy = py;                                      \
            if (r + 1 < R1) { /* prefetch row r+8 (< 512 guaranteed) */   \
                px = ld4(gx + (size_t)(r + 8) * W);                       \
                py = ld4(gy + (size_t)(r + 8) * W);                       \
            }                                                             \
            float4 ox = ring_x[slot], oy = ring_y[slot];                  \
            vsx = f4add(f4sub(vsx, ox), cx);                              \
            vsy = f4add(f4sub(vsy, oy), cy);                              \
            vsq = f4add(vsq, f4sub(f4add(f4mul(cx, cx), f4mul(cy, cy)),   \
                                   f4add(f4mul(ox, ox), f4mul(oy, oy)))); \
            vsp = f4add(vsp, f4sub(f4mul(cx, cy), f4mul(ox, oy)));        \
            ring_x[slot] = cx; ring_y[slot] = cy;                         \
            *(float4*)&vbuf[0][c0] = vsx;                                 \
            *(float4*)&vbuf[1][c0] = vsy;                                 \
            *(float4*)&vbuf[2][c0] = vsq;                                 \
            *(float4*)&vbuf[3][c0] = vsp;                                 \
            __syncthreads();                                              \
            float B[4][4];                                                \
            HORIZ(0, vsx); HORIZ(1, vsy); HORIZ(2, vsq); HORIZ(3, vsp);   \
            __syncthreads(); /* WAR guard before next row's LDS writes */ \
            _Pragma("unroll")                                             \
            for (int j = 0; j < 4; ++j) {                                 \
                float Sx = B[0][j], Sy = B[1][j];                         \
                float Sq = B[2][j], Sp = B[3][j];                         \
                float mu12 = Sx * Sy;                                     \
                float n1v = 2.0f * mu12 + C1;                             \
                float n2v = 2.0f * (Sp - mu12) + C2;                      \
                float sx2 = Sx * Sx, sy2 = Sy * Sy;                       \
                float d1  = sx2 + sy2 + C1;                               \
                float d2  = (Sq - sx2 - sy2) + C2;                        \
                float sv  = (n1v * n2v) * __builtin_amdgcn_rcpf(d1 * d2); \
                if (c0 + j < OW) acc += sv;                               \
            }                                                             \
        }                                                                 \
    }

    // R0 and rbase are multiples of 8, so ring slot (r+7)&7 = (k+7)&7 (literal).
    for (int rbase = R0; rbase < R1; rbase += 8) {
        ROWBODY(0, 7)
        ROWBODY(1, 0)
        ROWBODY(2, 1)
        ROWBODY(3, 2)
        ROWBODY(4, 3)
        ROWBODY(5, 4)
        ROWBODY(6, 5)
        ROWBODY(7, 6)
    }

    // reduction: wave shuffle -> LDS -> one double atomic per block
#pragma unroll
    for (int off = 32; off > 0; off >>= 1) acc += __shfl_down(acc, off);
    const int wave = t >> 6, lane = t & 63;
    if (lane == 0) wpart[wave] = acc;
    __syncthreads();
    if (t == 0) atomicAdd(acc_out, (double)(wpart[0] + wpart[1]));
}

extern "C" void kernel_launch(void* const* d_in, const int* in_sizes, int n_in,
                              void* d_out, int out_size, void* d_ws, size_t ws_size,
                              hipStream_t stream) {
    const float* gt = (const float*)d_in[0];
    const float* ni = (const float*)d_in[1];
    double* acc = (double*)d_ws;   // 8 bytes scratch, re-zeroed every call

    zero_ws<<<1, 1, 0, stream>>>(acc);
    dim3 grid(NSTRIP, NIMG);
    ssim_main<<<grid, 128, 0, stream>>>(gt, ni, acc);
    finalize<<<1, 1, 0, stream>>>(acc, (float*)d_out);
}